// Round 1
// baseline (4186.783 us; speedup 1.0000x reference)
//
#include <hip/hip_runtime.h>

// ---------------------------------------------------------------------------
// BiLSTM w2v: embed+relu -> x_proj GEMM (f16 dot2) -> 2x sequential LSTM scan
// (Whh in registers as f16 pairs, fp32 accum) -> h2s relu -> s2o.
// ---------------------------------------------------------------------------

#define T_SEQ 4096
#define E_DIM 300
#define H_DIM 200
#define G4    800     // 4*H (gate rows per direction)
#define N2    1600    // gate rows, both directions
#define KP    150     // E/2 f16 pairs
#define XH_DIM 50
#define O_DIM 2

typedef _Float16 h2v __attribute__((ext_vector_type(2)));

#if defined(__has_builtin)
#  if __has_builtin(__builtin_amdgcn_fdot2)
#    define HAS_FDOT2 1
#  endif
#endif

__device__ __forceinline__ h2v bc2(unsigned u) { return __builtin_bit_cast(h2v, u); }

__device__ __forceinline__ float dot2f(h2v a, h2v b, float c) {
#ifdef HAS_FDOT2
  return __builtin_amdgcn_fdot2(a, b, c, false);   // v_dot2_f32_f16, f32 accum
#else
  return c + (float)a[0] * (float)b[0] + (float)a[1] * (float)b[1];
#endif
}

__device__ __forceinline__ float fsigmoid(float x) {
  return __builtin_amdgcn_rcpf(1.f + __expf(-x));
}
__device__ __forceinline__ float ftanh(float x) {
  float e = __expf(-2.f * x);
  return (1.f - e) * __builtin_amdgcn_rcpf(1.f + e);
}

// ---- prep: f32 -> f16-pair weight conversion + bias sum -------------------
// W2   : [1600][150] f16-pairs (Wih_f rows 0..799, Wih_b rows 800..1599)
// WhhT : [2][ (g*20+c)*5 + rc ][200] f16-pairs, scan-coalesced layout
// bsum : [1600] f32 = bih + bhh per direction
__global__ __launch_bounds__(256) void prep_weights(
    const float* __restrict__ WihF, const float* __restrict__ WihB,
    const float* __restrict__ WhhF, const float* __restrict__ WhhB,
    const float* __restrict__ bihF, const float* __restrict__ bhhF,
    const float* __restrict__ bihB, const float* __restrict__ bhhB,
    unsigned* __restrict__ W2, unsigned* __restrict__ WhhT,
    float* __restrict__ bsum)
{
  int i = blockIdx.x * 256 + threadIdx.x;
  if (i < 240000) {                       // W2
    int j = i / KP, k = i - j * KP;
    const float* src = (j < G4) ? (WihF + (size_t)j * E_DIM)
                                : (WihB + (size_t)(j - G4) * E_DIM);
    h2v p = { (_Float16)src[2 * k], (_Float16)src[2 * k + 1] };
    W2[i] = __builtin_bit_cast(unsigned, p);
  } else if (i < 400000) {                // WhhT (permuted for coalesced scan load)
    int ii = i - 240000;
    int dir = ii / 80000; int rem = ii - dir * 80000;
    int g  = rem / 20000;  rem -= g * 20000;
    int c  = rem / 1000;   rem -= c * 1000;
    int rc = rem / 200;    int r0 = rem - rc * 200;
    const float* src = dir ? WhhB : WhhF;
    int row = r0 + 200 * g;
    int col = 2 * (rc * 20 + c);
    h2v p = { (_Float16)src[row * H_DIM + col], (_Float16)src[row * H_DIM + col + 1] };
    WhhT[ii] = __builtin_bit_cast(unsigned, p);
  } else if (i < 401600) {                // bsum
    int j = i - 400000;
    bsum[j] = (j < G4) ? (bihF[j] + bhhF[j]) : (bihB[j - G4] + bhhB[j - G4]);
  }
}

// ---- embedding gather + relu -> f16 pairs ---------------------------------
__global__ __launch_bounds__(256) void embed_relu(
    const int* __restrict__ x, const float* __restrict__ emb,
    unsigned* __restrict__ sent2)
{
  int i = blockIdx.x * 256 + threadIdx.x;
  if (i >= T_SEQ * KP) return;
  int t = i / KP, k = i - t * KP;
  int row = x[t];
  float a = emb[(size_t)row * E_DIM + 2 * k];
  float b = emb[(size_t)row * E_DIM + 2 * k + 1];
  a = fmaxf(a, 0.f); b = fmaxf(b, 0.f);
  h2v p = { (_Float16)a, (_Float16)b };
  sent2[i] = __builtin_bit_cast(unsigned, p);
}

// ---- x_proj GEMM: xp[t][j] = bsum[j] + sum_k sent[t][k]*Wih[j][k] ---------
// 64x64 tile per 256-thread block, full K (150 pairs) staged in LDS
// transposed [k][row] (+pad to 68 for b128 alignment / bank spread).
__global__ __launch_bounds__(256) void xproj_gemm(
    const unsigned* __restrict__ sent2, const unsigned* __restrict__ W2,
    const float* __restrict__ bsum, float* __restrict__ xp)
{
  __shared__ alignas(16) unsigned sL[KP][68];
  __shared__ alignas(16) unsigned wL[KP][68];
  const int t0 = blockIdx.x * 64, j0 = blockIdx.y * 64;

  for (int idx = threadIdx.x; idx < 64 * KP; idx += 256) {
    int r = idx / KP, c = idx - r * KP;
    sL[c][r] = sent2[t0 * KP + idx];
    wL[c][r] = W2[j0 * KP + idx];
  }

  const int tx = threadIdx.x & 15, ty = threadIdx.x >> 4;
  float acc[4][4];
  #pragma unroll
  for (int jj = 0; jj < 4; ++jj) {
    float bv = bsum[j0 + tx * 4 + jj];
    #pragma unroll
    for (int ti = 0; ti < 4; ++ti) acc[ti][jj] = bv;
  }
  __syncthreads();

  uint4 sv = *reinterpret_cast<const uint4*>(&sL[0][ty * 4]);
  uint4 wv = *reinterpret_cast<const uint4*>(&wL[0][tx * 4]);
  for (int k = 0; k < KP; ++k) {
    uint4 svn, wvn;
    if (k + 1 < KP) {   // software prefetch: hide LDS latency under the dots
      svn = *reinterpret_cast<const uint4*>(&sL[k + 1][ty * 4]);
      wvn = *reinterpret_cast<const uint4*>(&wL[k + 1][tx * 4]);
    }
    h2v ss[4] = { bc2(sv.x), bc2(sv.y), bc2(sv.z), bc2(sv.w) };
    h2v ww[4] = { bc2(wv.x), bc2(wv.y), bc2(wv.z), bc2(wv.w) };
    #pragma unroll
    for (int ti = 0; ti < 4; ++ti)
      #pragma unroll
      for (int jj = 0; jj < 4; ++jj)
        acc[ti][jj] = dot2f(ss[ti], ww[jj], acc[ti][jj]);
    sv = svn; wv = wvn;
  }

  #pragma unroll
  for (int ti = 0; ti < 4; ++ti) {
    float4 o = { acc[ti][0], acc[ti][1], acc[ti][2], acc[ti][3] };
    *reinterpret_cast<float4*>(&xp[(size_t)(t0 + ty * 4 + ti) * N2 + j0 + tx * 4]) = o;
  }
}

// ---- the sequential LSTM scan ---------------------------------------------
// One block per direction (grid=2). 1024 threads; 1000 active in the matvec:
// thread (rc = tid/200, r0 = tid%200) owns gate rows {r0+200g, g=0..3} x
// cols [40*rc, 40*rc+40) of Whh, held in registers as 80 f16-pair dwords.
// Per step: phase1 = 80 dot2/thread + 4 LDS partial writes; barrier;
// phase2 (tid<200) = 20 partial reads + activations + c/h update + h->LDS f16;
// barrier. c lives in thread-tid registers. xp prefetched one step ahead.
__global__ __launch_bounds__(1024) void lstm_scan(
    const unsigned* __restrict__ WhhT, const float* __restrict__ xp,
    float* __restrict__ hs)
{
  const int dir = blockIdx.x;
  const int tid = threadIdx.x;
  __shared__ alignas(16) float    part[5][800];   // 16 KB partial gate sums
  __shared__ alignas(16) unsigned hbuf[104];      // h as f16 pairs (100 used)

  const unsigned* Wd  = WhhT + dir * 80000;
  const float*    xpd = xp + dir * 800;           // row stride N2
  float*          hsd = hs + dir * 200;           // row stride 400

  const int  rc   = tid / 200;
  const int  r0   = tid - rc * 200;
  const bool act1 = (tid < 1000);

  h2v w[4][20];
  if (act1) {
    #pragma unroll
    for (int g = 0; g < 4; ++g)
      #pragma unroll
      for (int c = 0; c < 20; ++c)
        w[g][c] = bc2(Wd[(g * 20 + c) * 1000 + rc * 200 + r0]);  // coalesced
  }

  float xv0 = 0.f, xv1 = 0.f, xv2 = 0.f, xv3 = 0.f;
  float creg = 0.f;
  if (tid < 200) {
    xv0 = xpd[tid]; xv1 = xpd[200 + tid]; xv2 = xpd[400 + tid]; xv3 = xpd[600 + tid];
  }
  if (tid < 104) hbuf[tid] = 0u;   // h_0 = 0
  __syncthreads();

  const uint4* hb4 = reinterpret_cast<const uint4*>(hbuf) + rc * 5;

  for (int t = 0; t < T_SEQ; ++t) {
    // prefetch next step's x_proj (hidden under phase 1 + phase 2)
    float xn0 = 0.f, xn1 = 0.f, xn2 = 0.f, xn3 = 0.f;
    if (tid < 200 && t + 1 < T_SEQ) {
      const float* xr = xpd + (size_t)(t + 1) * N2;
      xn0 = xr[tid]; xn1 = xr[200 + tid]; xn2 = xr[400 + tid]; xn3 = xr[600 + tid];
    }

    if (act1) {
      float a0 = 0.f, a1 = 0.f, a2 = 0.f, a3 = 0.f;
      #pragma unroll
      for (int c4 = 0; c4 < 5; ++c4) {
        uint4 hv = hb4[c4];                       // broadcast read
        h2v h0 = bc2(hv.x), h1 = bc2(hv.y), hq2 = bc2(hv.z), h3 = bc2(hv.w);
        a0 = dot2f(w[0][c4 * 4 + 0], h0, a0);
        a1 = dot2f(w[1][c4 * 4 + 0], h0, a1);
        a2 = dot2f(w[2][c4 * 4 + 0], h0, a2);
        a3 = dot2f(w[3][c4 * 4 + 0], h0, a3);
        a0 = dot2f(w[0][c4 * 4 + 1], h1, a0);
        a1 = dot2f(w[1][c4 * 4 + 1], h1, a1);
        a2 = dot2f(w[2][c4 * 4 + 1], h1, a2);
        a3 = dot2f(w[3][c4 * 4 + 1], h1, a3);
        a0 = dot2f(w[0][c4 * 4 + 2], hq2, a0);
        a1 = dot2f(w[1][c4 * 4 + 2], hq2, a1);
        a2 = dot2f(w[2][c4 * 4 + 2], hq2, a2);
        a3 = dot2f(w[3][c4 * 4 + 2], hq2, a3);
        a0 = dot2f(w[0][c4 * 4 + 3], h3, a0);
        a1 = dot2f(w[1][c4 * 4 + 3], h3, a1);
        a2 = dot2f(w[2][c4 * 4 + 3], h3, a2);
        a3 = dot2f(w[3][c4 * 4 + 3], h3, a3);
      }
      part[rc][r0]       = a0;
      part[rc][r0 + 200] = a1;
      part[rc][r0 + 400] = a2;
      part[rc][r0 + 600] = a3;
    }
    __syncthreads();

    if (tid < 200) {
      float g0 = xv0, g1 = xv1, g2 = xv2, g3 = xv3;   // bias already in xp
      #pragma unroll
      for (int q = 0; q < 5; ++q) {
        g0 += part[q][tid];
        g1 += part[q][200 + tid];
        g2 += part[q][400 + tid];
        g3 += part[q][600 + tid];
      }
      float iv = fsigmoid(g0);
      float fv = fsigmoid(g1);
      float gv = ftanh(g2);
      float ov = fsigmoid(g3);
      creg = fv * creg + iv * gv;
      float hval = ov * ftanh(creg);
      hsd[(size_t)t * 400 + tid] = hval;                       // for h2s
      reinterpret_cast<_Float16*>(hbuf)[tid] = (_Float16)hval; // for next matvec
      xv0 = xn0; xv1 = xn1; xv2 = xn2; xv3 = xn3;
    }
    __syncthreads();
  }
}

// ---- s = relu(hs @ W_h2s + b) ---------------------------------------------
__global__ __launch_bounds__(256) void h2s_kernel(
    const float* __restrict__ hs, const float* __restrict__ W,
    const float* __restrict__ b, float* __restrict__ s)
{
  int i = blockIdx.x * 256 + threadIdx.x;
  if (i >= T_SEQ * XH_DIM) return;
  int t = i / XH_DIM, xh = i - t * XH_DIM;
  const float* hr = hs + (size_t)t * 400;
  float a0 = b[xh], a1 = 0.f, a2 = 0.f, a3 = 0.f;
  for (int j = 0; j < 400; j += 4) {
    a0 += hr[j]     * W[(j)     * XH_DIM + xh];
    a1 += hr[j + 1] * W[(j + 1) * XH_DIM + xh];
    a2 += hr[j + 2] * W[(j + 2) * XH_DIM + xh];
    a3 += hr[j + 3] * W[(j + 3) * XH_DIM + xh];
  }
  s[i] = fmaxf((a0 + a1) + (a2 + a3), 0.f);
}

// ---- out = s @ W_s2o + b --------------------------------------------------
__global__ __launch_bounds__(256) void s2o_kernel(
    const float* __restrict__ s, const float* __restrict__ W,
    const float* __restrict__ b, float* __restrict__ out)
{
  int t = blockIdx.x * 256 + threadIdx.x;
  if (t >= T_SEQ) return;
  float a0 = b[0], a1 = b[1];
  for (int xh = 0; xh < XH_DIM; ++xh) {
    float sv = s[t * XH_DIM + xh];
    a0 += sv * W[xh * 2];
    a1 += sv * W[xh * 2 + 1];
  }
  out[t * 2]     = a0;
  out[t * 2 + 1] = a1;
}

// ---------------------------------------------------------------------------
extern "C" void kernel_launch(void* const* d_in, const int* in_sizes, int n_in,
                              void* d_out, int out_size, void* d_ws, size_t ws_size,
                              hipStream_t stream)
{
  (void)in_sizes; (void)n_in; (void)out_size; (void)ws_size;
  const int*   x    = (const int*)d_in[0];
  const float* emb  = (const float*)d_in[1];
  const float* WihF = (const float*)d_in[2];
  const float* WhhF = (const float*)d_in[3];
  const float* bihF = (const float*)d_in[4];
  const float* bhhF = (const float*)d_in[5];
  const float* WihB = (const float*)d_in[6];
  const float* WhhB = (const float*)d_in[7];
  const float* bihB = (const float*)d_in[8];
  const float* bhhB = (const float*)d_in[9];
  const float* Wh2s = (const float*)d_in[10];
  const float* bh2s = (const float*)d_in[11];
  const float* Ws2o = (const float*)d_in[12];
  const float* bs2o = (const float*)d_in[13];

  char* p = (char*)d_ws;
  unsigned* sent2 = (unsigned*)p; p += (size_t)T_SEQ * KP * 4;   // 2.46 MB
  unsigned* W2    = (unsigned*)p; p += (size_t)240000 * 4;       // 0.96 MB
  unsigned* WhhT  = (unsigned*)p; p += (size_t)160000 * 4;       // 0.64 MB
  float* bsum = (float*)p;        p += (size_t)1600 * 4;
  float* xp   = (float*)p;        p += (size_t)T_SEQ * N2 * 4;   // 26.2 MB
  float* hs   = (float*)p;        p += (size_t)T_SEQ * 400 * 4;  // 6.55 MB
  float* s    = (float*)p;        p += (size_t)T_SEQ * XH_DIM * 4;

  prep_weights<<<1569, 256, 0, stream>>>(WihF, WihB, WhhF, WhhB,
                                         bihF, bhhF, bihB, bhhB, W2, WhhT, bsum);
  embed_relu<<<2400, 256, 0, stream>>>(x, emb, sent2);
  xproj_gemm<<<dim3(64, 25), 256, 0, stream>>>(sent2, W2, bsum, xp);
  lstm_scan<<<2, 1024, 0, stream>>>(WhhT, xp, hs);
  h2s_kernel<<<800, 256, 0, stream>>>(hs, Wh2s, bh2s, s);
  s2o_kernel<<<16, 256, 0, stream>>>(s, Ws2o, bs2o, (float*)d_out);
}